// Round 4
// baseline (65.327 us; speedup 1.0000x reference)
//
#include <hip/hip_runtime.h>
#include <hip/hip_bf16.h>
#include <math.h>

#define Bn 2
#define Kn 8
#define Cn 256
#define HWn (128*128)
#define Sn 2048
#define BTM 128   // block rows
#define BTN 128   // block cols (8 waves: 2 row-slabs x 4 col-slabs of 64x32)
#define SIM_BLOCKS ((Sn/BTM)*(Sn/BTN)*Bn)   // 512

typedef __bf16 bf16x8 __attribute__((ext_vector_type(8)));
typedef float  f32x4  __attribute__((ext_vector_type(4)));

// Wave per sample: lane loads 4 channels (c = lane + 64q) -> 4 outstanding
// misses/thread; butterfly-reduce ||f||^2; write bf16 row. Block 0 zeroes accum.
__global__ __launch_bounds__(256) void gather_kernel(
    const float* __restrict__ masks, const float* __restrict__ feats,
    const int* __restrict__ indices, ushort* __restrict__ fTb,
    float* __restrict__ mS, float* __restrict__ accum)
{
    if (blockIdx.x == 0 && threadIdx.x < 4) accum[threadIdx.x] = 0.0f;

    const int wave = threadIdx.x >> 6;
    const int lane = threadIdx.x & 63;
    const int bs = blockIdx.x * 4 + wave;
    const int b  = bs >> 11;        // / Sn
    const int s  = bs & (Sn - 1);
    const int id = indices[b * Sn + s];

    const float* fb = feats + (size_t)b * Cn * HWn + id;
    float v[4];
    #pragma unroll
    for (int q = 0; q < 4; ++q)
        v[q] = fb[(size_t)(lane + 64 * q) * HWn];

    float x = v[0]*v[0] + v[1]*v[1] + v[2]*v[2] + v[3]*v[3];
    #pragma unroll
    for (int o = 32; o > 0; o >>= 1) x += __shfl_xor(x, o);
    const float scale = 1.0f / fmaxf(sqrtf(x), 1e-12f);

    #pragma unroll
    for (int q = 0; q < 4; ++q) {
        __hip_bfloat16 hv = __float2bfloat16(v[q] * scale);
        fTb[(size_t)bs * Cn + lane + 64 * q] = *reinterpret_cast<const ushort*>(&hv);
    }

    if (lane < Kn) {
        const float lg = masks[((size_t)(b * Kn + lane)) * HWn + id];
        mS[(size_t)bs * Kn + lane] = 1.0f / (1.0f + expf(-lg));
    }
}

// MFMA Gram matrix from L2-resident fTb (2 MB). 512 blocks x 8 waves;
// wave = 64x32 sub-tile (4x2 frags of 16x16x32 bf16). Register double-buffered
// k-loop (compile-time ping-pong) so next step's loads overlap current MFMAs.
__global__ __launch_bounds__(512, 4) void sim_kernel(
    const ushort* __restrict__ fTb, const float* __restrict__ mS,
    float* __restrict__ accum, float* __restrict__ out)
{
    const int b   = blockIdx.z;
    const int s0  = blockIdx.y * BTM;
    const int t0  = blockIdx.x * BTN;
    const int tid = threadIdx.x;
    const int lane = tid & 63;
    const int wave = tid >> 6;      // 0..7
    const int wm = wave >> 2;       // 0..1 : 64-row slab
    const int wn = wave & 3;        // 0..3 : 32-col slab
    const int l15 = lane & 15, l4 = lane >> 4;

    const ushort* F  = fTb + (size_t)b * Sn * Cn;
    const ushort* pA = F + (size_t)(s0 + wm * 64 + l15) * Cn + l4 * 8;
    const ushort* pB = F + (size_t)(t0 + wn * 32 + l15) * Cn + l4 * 8;

    f32x4 acc[4][2];
    #pragma unroll
    for (int m = 0; m < 4; ++m)
        #pragma unroll
        for (int n = 0; n < 2; ++n) acc[m][n] = (f32x4){0.f, 0.f, 0.f, 0.f};

    bf16x8 aF[2][4], bF[2][2];
    #pragma unroll
    for (int m = 0; m < 4; ++m)
        aF[0][m] = *reinterpret_cast<const bf16x8*>(pA + (size_t)m * 16 * Cn);
    #pragma unroll
    for (int n = 0; n < 2; ++n)
        bF[0][n] = *reinterpret_cast<const bf16x8*>(pB + (size_t)n * 16 * Cn);

    #pragma unroll
    for (int s = 0; s < 8; ++s) {       // fully unrolled: cur/nxt fold to consts
        const int cur = s & 1, nxt = cur ^ 1;
        if (s < 7) {
            const int k0 = (s + 1) * 32;
            #pragma unroll
            for (int m = 0; m < 4; ++m)
                aF[nxt][m] = *reinterpret_cast<const bf16x8*>(pA + (size_t)m * 16 * Cn + k0);
            #pragma unroll
            for (int n = 0; n < 2; ++n)
                bF[nxt][n] = *reinterpret_cast<const bf16x8*>(pB + (size_t)n * 16 * Cn + k0);
        }
        #pragma unroll
        for (int m = 0; m < 4; ++m)
            #pragma unroll
            for (int n = 0; n < 2; ++n)
                acc[m][n] = __builtin_amdgcn_mfma_f32_16x16x32_bf16(
                    aF[cur][m], bF[cur][n], acc[m][n], 0, 0, 0);
    }

    // C/D layout: col = lane&15, row = (lane>>4)*4 + reg  [HW-verified m89]
    float num_l = 0.0f, den_l = 0.0f;
    const float* mSb = mS + (size_t)b * Sn * Kn;
    #pragma unroll
    for (int m = 0; m < 4; ++m) {
        #pragma unroll
        for (int n = 0; n < 2; ++n) {
            #pragma unroll
            for (int r = 0; r < 4; ++r) {
                if (acc[m][n][r] > 0.95f) {
                    den_l += 1.0f;
                    const int srow = s0 + wm * 64 + m * 16 + l4 * 4 + r;
                    const int tcol = t0 + wn * 32 + n * 16 + l15;
                    const float* ma = mSb + (size_t)srow * Kn;
                    const float* mb = mSb + (size_t)tcol * Kn;
                    #pragma unroll
                    for (int k = 0; k < Kn; ++k) num_l += fabsf(ma[k] - mb[k]);
                }
            }
        }
    }

    #pragma unroll
    for (int o = 32; o > 0; o >>= 1) {
        num_l += __shfl_down(num_l, o);
        den_l += __shfl_down(den_l, o);
    }
    __shared__ float rn[8], rd[8];
    if (lane == 0) { rn[wave] = num_l; rd[wave] = den_l; }
    __syncthreads();
    if (tid == 0) {
        float nn = 0.f, dd = 0.f;
        #pragma unroll
        for (int w = 0; w < 8; ++w) { nn += rn[w]; dd += rd[w]; }
        atomicAdd(&accum[0], nn);
        atomicAdd(&accum[1], dd);
        __threadfence();   // release partials before counter bump
        unsigned* cnt = reinterpret_cast<unsigned*>(&accum[2]);
        const unsigned done = atomicAdd(cnt, 1u);
        if (done == SIM_BLOCKS - 1) {
            const float fn = atomicAdd(&accum[0], 0.0f);   // device-scope read
            const float fd = atomicAdd(&accum[1], 0.0f);
            out[0] = fn / (fd + 1e-6f);
        }
    }
}

extern "C" void kernel_launch(void* const* d_in, const int* in_sizes, int n_in,
                              void* d_out, int out_size, void* d_ws, size_t ws_size,
                              hipStream_t stream) {
    const float* masks   = (const float*)d_in[0];   // (B,K,H,W) fp32
    const float* feats   = (const float*)d_in[1];   // (B,C,H,W) fp32
    const int*   indices = (const int*)d_in[2];     // (B,S) int32
    float* out = (float*)d_out;

    // ws: fTb (B*S*C bf16 = 2 MB) | mS (B*S*K f32 = 128 KB) | accum (4 f32)
    ushort* fTb  = (ushort*)d_ws;
    float*  mSm  = (float*)((char*)d_ws + (size_t)Bn * Sn * Cn * sizeof(ushort));
    float*  accum = mSm + (size_t)Bn * Sn * Kn;

    gather_kernel<<<Bn * Sn / 4, 256, 0, stream>>>(masks, feats, indices, fTb, mSm, accum);
    dim3 grid(Sn / BTN, Sn / BTM, Bn);
    sim_kernel<<<grid, 512, 0, stream>>>(fTb, mSm, accum, out);
}

// Round 5
// 50.878 us; speedup vs baseline: 1.2840x; 1.2840x over previous
//
#include <hip/hip_runtime.h>
#include <hip/hip_bf16.h>
#include <math.h>

#define Bn 2
#define Kn 8
#define Cn 256
#define HWn (128*128)
#define Sn 2048
#define BT 128            // block output tile (4 waves, 2x2 of 64x64)
#define BK 64             // k-step staged per LDS buffer
#define NSTEP (Cn / BK)   // 4
#define SIM_BLOCKS ((Sn/BT)*(Sn/BT)*Bn)   // 512

typedef __bf16 bf16x8 __attribute__((ext_vector_type(8)));
typedef float  f32x4  __attribute__((ext_vector_type(4)));

__device__ __forceinline__ void gload_lds16(const ushort* g, ushort* l) {
    __builtin_amdgcn_global_load_lds(
        (const __attribute__((address_space(1))) void*)g,
        (__attribute__((address_space(3))) void*)l,
        16, 0, 0);
}

// Wave per sample: lane loads 4 channels -> 4 outstanding misses/thread;
// butterfly-reduce ||f||^2; write bf16 row. Block 0 zeroes accum.
__global__ __launch_bounds__(256) void gather_kernel(
    const float* __restrict__ masks, const float* __restrict__ feats,
    const int* __restrict__ indices, ushort* __restrict__ fTb,
    float* __restrict__ mS, float* __restrict__ accum)
{
    if (blockIdx.x == 0 && threadIdx.x < 4) accum[threadIdx.x] = 0.0f;

    const int wave = threadIdx.x >> 6;
    const int lane = threadIdx.x & 63;
    const int bs = blockIdx.x * 4 + wave;
    const int b  = bs >> 11;
    const int s  = bs & (Sn - 1);
    const int id = indices[b * Sn + s];

    const float* fb = feats + (size_t)b * Cn * HWn + id;
    float v[4];
    #pragma unroll
    for (int q = 0; q < 4; ++q)
        v[q] = fb[(size_t)(lane + 64 * q) * HWn];

    float x = v[0]*v[0] + v[1]*v[1] + v[2]*v[2] + v[3]*v[3];
    #pragma unroll
    for (int o = 32; o > 0; o >>= 1) x += __shfl_xor(x, o);
    const float scale = 1.0f / fmaxf(sqrtf(x), 1e-12f);

    #pragma unroll
    for (int q = 0; q < 4; ++q) {
        __hip_bfloat16 hv = __float2bfloat16(v[q] * scale);
        fTb[(size_t)bs * Cn + lane + 64 * q] = *reinterpret_cast<const ushort*>(&hv);
    }

    if (lane < Kn) {
        const float lg = masks[((size_t)(b * Kn + lane)) * HWn + id];
        mS[(size_t)bs * Kn + lane] = 1.0f / (1.0f + expf(-lg));
    }
}

// MFMA Gram matrix, m97-structure: global_load_lds double-buffered staging,
// XOR-swizzled (linear LDS dest + inverse-swizzled global source + swizzled
// ds_read). 4 waves (2x2), each 64x64 = 4x4 frags of 16x16x32 bf16.
__global__ __launch_bounds__(256, 2) void sim_kernel(
    const ushort* __restrict__ fTb, const float* __restrict__ mS,
    float* __restrict__ accum, float* __restrict__ out)
{
    // [buf][row][chunk]: 2 x 128 rows x 8 chunks of 8 bf16 (row = 64 ushorts)
    __shared__ ushort ldsA[2][BT * BK];
    __shared__ ushort ldsB[2][BT * BK];

    const int b   = blockIdx.z;
    const int s0  = blockIdx.y * BT;
    const int t0  = blockIdx.x * BT;
    const int tid = threadIdx.x;
    const int lane = tid & 63;
    const int wave = tid >> 6;          // 0..3
    const int wm = wave >> 1, wn = wave & 1;
    const int l15 = lane & 15, l4 = lane >> 4;

    const ushort* FA = fTb + ((size_t)(b * Sn + s0)) * Cn;
    const ushort* FB = fTb + ((size_t)(b * Sn + t0)) * Cn;

    // --- staging: tile = 1024 chunks of 16B; wave w covers chunks [w*256, w*256+256)
    // LDS slot (row, c) receives global chunk (c ^ (row&7))  [involution swizzle]
    const int qw = wave * 256;
    #define STAGE(buf, k0)                                                     \
    {                                                                          \
        _Pragma("unroll")                                                      \
        for (int i = 0; i < 4; ++i) {                                          \
            const int q   = qw + i * 64 + lane;                                \
            const int row = q >> 3;                                            \
            const int csw = (q & 7) ^ (row & 7);                               \
            const size_t goff = (size_t)row * Cn + (k0) + csw * 8;             \
            gload_lds16(FA + goff, &ldsA[buf][(qw + i * 64) * 8]);             \
            gload_lds16(FB + goff, &ldsB[buf][(qw + i * 64) * 8]);             \
        }                                                                      \
    }

    f32x4 acc[4][4];
    #pragma unroll
    for (int m = 0; m < 4; ++m)
        #pragma unroll
        for (int n = 0; n < 4; ++n) acc[m][n] = (f32x4){0.f, 0.f, 0.f, 0.f};

    STAGE(0, 0);
    __syncthreads();

    #pragma unroll
    for (int s = 0; s < NSTEP; ++s) {
        const int buf = s & 1;
        if (s + 1 < NSTEP) STAGE(buf ^ 1, (s + 1) * BK);

        #pragma unroll
        for (int kk = 0; kk < BK; kk += 32) {
            const int g = (kk >> 3) + l4;           // global chunk 0..7
            bf16x8 aF[4], bF[4];
            #pragma unroll
            for (int m = 0; m < 4; ++m) {
                const int row = wm * 64 + m * 16 + l15;
                aF[m] = *reinterpret_cast<const bf16x8*>(
                    &ldsA[buf][row * BK + ((g ^ (row & 7)) << 3)]);
            }
            #pragma unroll
            for (int n = 0; n < 4; ++n) {
                const int row = wn * 64 + n * 16 + l15;
                bF[n] = *reinterpret_cast<const bf16x8*>(
                    &ldsB[buf][row * BK + ((g ^ (row & 7)) << 3)]);
            }
            #pragma unroll
            for (int m = 0; m < 4; ++m)
                #pragma unroll
                for (int n = 0; n < 4; ++n)
                    acc[m][n] = __builtin_amdgcn_mfma_f32_16x16x32_bf16(
                        aF[m], bF[n], acc[m][n], 0, 0, 0);
        }
        __syncthreads();
    }

    // C/D layout: col = lane&15, row = (lane>>4)*4 + reg  [HW-verified m89]
    float num_l = 0.0f, den_l = 0.0f;
    const float* mSb = mS + (size_t)b * Sn * Kn;
    #pragma unroll
    for (int m = 0; m < 4; ++m) {
        #pragma unroll
        for (int n = 0; n < 4; ++n) {
            #pragma unroll
            for (int r = 0; r < 4; ++r) {
                if (acc[m][n][r] > 0.95f) {
                    den_l += 1.0f;
                    const int srow = s0 + wm * 64 + m * 16 + l4 * 4 + r;
                    const int tcol = t0 + wn * 64 + n * 16 + l15;
                    const float* ma = mSb + (size_t)srow * Kn;
                    const float* mb = mSb + (size_t)tcol * Kn;
                    #pragma unroll
                    for (int k = 0; k < Kn; ++k) num_l += fabsf(ma[k] - mb[k]);
                }
            }
        }
    }

    #pragma unroll
    for (int o = 32; o > 0; o >>= 1) {
        num_l += __shfl_down(num_l, o);
        den_l += __shfl_down(den_l, o);
    }
    __shared__ float rn[4], rd[4];
    if (lane == 0) { rn[wave] = num_l; rd[wave] = den_l; }
    __syncthreads();
    if (tid == 0) {
        atomicAdd(&accum[0], rn[0] + rn[1] + rn[2] + rn[3]);
        atomicAdd(&accum[1], rd[0] + rd[1] + rd[2] + rd[3]);
        __threadfence();
        unsigned* cnt = reinterpret_cast<unsigned*>(&accum[2]);
        const unsigned done = atomicAdd(cnt, 1u);
        if (done == SIM_BLOCKS - 1) {
            const float fn = atomicAdd(&accum[0], 0.0f);
            const float fd = atomicAdd(&accum[1], 0.0f);
            out[0] = fn / (fd + 1e-6f);
        }
    }
}

extern "C" void kernel_launch(void* const* d_in, const int* in_sizes, int n_in,
                              void* d_out, int out_size, void* d_ws, size_t ws_size,
                              hipStream_t stream) {
    const float* masks   = (const float*)d_in[0];   // (B,K,H,W) fp32
    const float* feats   = (const float*)d_in[1];   // (B,C,H,W) fp32
    const int*   indices = (const int*)d_in[2];     // (B,S) int32
    float* out = (float*)d_out;

    // ws: fTb (B*S*C bf16 = 2 MB) | mS (B*S*K f32 = 128 KB) | accum (4 f32)
    ushort* fTb  = (ushort*)d_ws;
    float*  mSm  = (float*)((char*)d_ws + (size_t)Bn * Sn * Cn * sizeof(ushort));
    float*  accum = mSm + (size_t)Bn * Sn * Kn;

    gather_kernel<<<Bn * Sn / 4, 256, 0, stream>>>(masks, feats, indices, fTb, mSm, accum);
    dim3 grid(Sn / BT, Sn / BT, Bn);
    sim_kernel<<<grid, 256, 0, stream>>>(fTb, mSm, accum, out);
}

// Round 6
// 35.477 us; speedup vs baseline: 1.8414x; 1.4341x over previous
//
#include <hip/hip_runtime.h>
#include <hip/hip_bf16.h>
#include <math.h>

#define Bn 2
#define Kn 8
#define Cn 256
#define HWn (128*128)
#define Sn 2048
#define BT 128            // block output tile (4 waves, 2x2 of 64x64)
#define BK 64             // k-step staged per LDS buffer
#define NSTEP (Cn / BK)   // 4
#define SIM_BLOCKS ((Sn/BT)*(Sn/BT)*Bn)   // 512

typedef __bf16 bf16x8 __attribute__((ext_vector_type(8)));
typedef float  f32x4  __attribute__((ext_vector_type(4)));

__device__ __forceinline__ void gload_lds16(const ushort* g, ushort* l) {
    __builtin_amdgcn_global_load_lds(
        (const __attribute__((address_space(1))) void*)g,
        (__attribute__((address_space(3))) void*)l,
        16, 0, 0);
}

// Wave per sample: lane loads 4 channels -> 4 outstanding misses/thread;
// butterfly-reduce ||f||^2; write bf16 row.
__global__ __launch_bounds__(256) void gather_kernel(
    const float* __restrict__ masks, const float* __restrict__ feats,
    const int* __restrict__ indices, ushort* __restrict__ fTb,
    float* __restrict__ mS)
{
    const int wave = threadIdx.x >> 6;
    const int lane = threadIdx.x & 63;
    const int bs = blockIdx.x * 4 + wave;
    const int b  = bs >> 11;
    const int s  = bs & (Sn - 1);
    const int id = indices[b * Sn + s];

    const float* fb = feats + (size_t)b * Cn * HWn + id;
    float v[4];
    #pragma unroll
    for (int q = 0; q < 4; ++q)
        v[q] = fb[(size_t)(lane + 64 * q) * HWn];

    float x = v[0]*v[0] + v[1]*v[1] + v[2]*v[2] + v[3]*v[3];
    #pragma unroll
    for (int o = 32; o > 0; o >>= 1) x += __shfl_xor(x, o);
    const float scale = 1.0f / fmaxf(sqrtf(x), 1e-12f);

    #pragma unroll
    for (int q = 0; q < 4; ++q) {
        __hip_bfloat16 hv = __float2bfloat16(v[q] * scale);
        fTb[(size_t)bs * Cn + lane + 64 * q] = *reinterpret_cast<const ushort*>(&hv);
    }

    if (lane < Kn) {
        const float lg = masks[((size_t)(b * Kn + lane)) * HWn + id];
        mS[(size_t)bs * Kn + lane] = 1.0f / (1.0f + expf(-lg));
    }
}

// MFMA Gram matrix, m97-structure: global_load_lds double-buffered staging,
// XOR-swizzled. 4 waves (2x2), each 64x64 = 4x4 frags of 16x16x32 bf16.
// Per-block partials -> plain stores to part[] (NO atomics, NO fence).
__global__ __launch_bounds__(256, 2) void sim_kernel(
    const ushort* __restrict__ fTb, const float* __restrict__ mS,
    float* __restrict__ part)
{
    __shared__ ushort ldsA[2][BT * BK];
    __shared__ ushort ldsB[2][BT * BK];

    const int b   = blockIdx.z;
    const int s0  = blockIdx.y * BT;
    const int t0  = blockIdx.x * BT;
    const int tid = threadIdx.x;
    const int lane = tid & 63;
    const int wave = tid >> 6;          // 0..3
    const int wm = wave >> 1, wn = wave & 1;
    const int l15 = lane & 15, l4 = lane >> 4;

    const ushort* FA = fTb + ((size_t)(b * Sn + s0)) * Cn;
    const ushort* FB = fTb + ((size_t)(b * Sn + t0)) * Cn;

    // staging: tile = 1024 chunks of 16B; wave w covers chunks [w*256, w*256+256)
    // LDS slot (row, c) receives global chunk (c ^ (row&7))  [involution swizzle]
    const int qw = wave * 256;
    #define STAGE(buf, k0)                                                     \
    {                                                                          \
        _Pragma("unroll")                                                      \
        for (int i = 0; i < 4; ++i) {                                          \
            const int q   = qw + i * 64 + lane;                                \
            const int row = q >> 3;                                            \
            const int csw = (q & 7) ^ (row & 7);                               \
            const size_t goff = (size_t)row * Cn + (k0) + csw * 8;             \
            gload_lds16(FA + goff, &ldsA[buf][(qw + i * 64) * 8]);             \
            gload_lds16(FB + goff, &ldsB[buf][(qw + i * 64) * 8]);             \
        }                                                                      \
    }

    f32x4 acc[4][4];
    #pragma unroll
    for (int m = 0; m < 4; ++m)
        #pragma unroll
        for (int n = 0; n < 4; ++n) acc[m][n] = (f32x4){0.f, 0.f, 0.f, 0.f};

    STAGE(0, 0);
    __syncthreads();

    #pragma unroll
    for (int s = 0; s < NSTEP; ++s) {
        const int buf = s & 1;
        if (s + 1 < NSTEP) STAGE(buf ^ 1, (s + 1) * BK);

        #pragma unroll
        for (int kk = 0; kk < BK; kk += 32) {
            const int g = (kk >> 3) + l4;           // global chunk 0..7
            bf16x8 aF[4], bF[4];
            #pragma unroll
            for (int m = 0; m < 4; ++m) {
                const int row = wm * 64 + m * 16 + l15;
                aF[m] = *reinterpret_cast<const bf16x8*>(
                    &ldsA[buf][row * BK + ((g ^ (row & 7)) << 3)]);
            }
            #pragma unroll
            for (int n = 0; n < 4; ++n) {
                const int row = wn * 64 + n * 16 + l15;
                bF[n] = *reinterpret_cast<const bf16x8*>(
                    &ldsB[buf][row * BK + ((g ^ (row & 7)) << 3)]);
            }
            #pragma unroll
            for (int m = 0; m < 4; ++m)
                #pragma unroll
                for (int n = 0; n < 4; ++n)
                    acc[m][n] = __builtin_amdgcn_mfma_f32_16x16x32_bf16(
                        aF[m], bF[n], acc[m][n], 0, 0, 0);
        }
        __syncthreads();
    }

    // C/D layout: col = lane&15, row = (lane>>4)*4 + reg  [HW-verified m89]
    float num_l = 0.0f, den_l = 0.0f;
    const float* mSb = mS + (size_t)b * Sn * Kn;
    #pragma unroll
    for (int m = 0; m < 4; ++m) {
        #pragma unroll
        for (int n = 0; n < 4; ++n) {
            #pragma unroll
            for (int r = 0; r < 4; ++r) {
                if (acc[m][n][r] > 0.95f) {
                    den_l += 1.0f;
                    const int srow = s0 + wm * 64 + m * 16 + l4 * 4 + r;
                    const int tcol = t0 + wn * 64 + n * 16 + l15;
                    const float* ma = mSb + (size_t)srow * Kn;
                    const float* mb = mSb + (size_t)tcol * Kn;
                    #pragma unroll
                    for (int k = 0; k < Kn; ++k) num_l += fabsf(ma[k] - mb[k]);
                }
            }
        }
    }

    #pragma unroll
    for (int o = 32; o > 0; o >>= 1) {
        num_l += __shfl_down(num_l, o);
        den_l += __shfl_down(den_l, o);
    }
    __shared__ float rn[4], rd[4];
    if (lane == 0) { rn[wave] = num_l; rd[wave] = den_l; }
    __syncthreads();
    if (tid == 0) {
        const int bid = (blockIdx.z * gridDim.y + blockIdx.y) * gridDim.x + blockIdx.x;
        part[2 * bid]     = rn[0] + rn[1] + rn[2] + rn[3];
        part[2 * bid + 1] = rd[0] + rd[1] + rd[2] + rd[3];
    }
}

// Reduce 512 {num,den} pairs (4 KB) and write out = num/(den+eps).
__global__ __launch_bounds__(256) void finalize_kernel(
    const float* __restrict__ part, float* __restrict__ out)
{
    const int tid = threadIdx.x;
    float n = 0.f, d = 0.f;
    #pragma unroll
    for (int i = 0; i < SIM_BLOCKS / 256; ++i) {
        const float2 p = reinterpret_cast<const float2*>(part)[tid + 256 * i];
        n += p.x; d += p.y;
    }
    #pragma unroll
    for (int o = 32; o > 0; o >>= 1) {
        n += __shfl_down(n, o);
        d += __shfl_down(d, o);
    }
    __shared__ float sn[4], sd[4];
    if ((tid & 63) == 0) { sn[tid >> 6] = n; sd[tid >> 6] = d; }
    __syncthreads();
    if (tid == 0) {
        const float fn = sn[0] + sn[1] + sn[2] + sn[3];
        const float fd = sd[0] + sd[1] + sd[2] + sd[3];
        out[0] = fn / (fd + 1e-6f);
    }
}

extern "C" void kernel_launch(void* const* d_in, const int* in_sizes, int n_in,
                              void* d_out, int out_size, void* d_ws, size_t ws_size,
                              hipStream_t stream) {
    const float* masks   = (const float*)d_in[0];   // (B,K,H,W) fp32
    const float* feats   = (const float*)d_in[1];   // (B,C,H,W) fp32
    const int*   indices = (const int*)d_in[2];     // (B,S) int32
    float* out = (float*)d_out;

    // ws: fTb (B*S*C bf16 = 2 MB) | mS (B*S*K f32 = 128 KB) | part (512*2 f32)
    ushort* fTb  = (ushort*)d_ws;
    float*  mSm  = (float*)((char*)d_ws + (size_t)Bn * Sn * Cn * sizeof(ushort));
    float*  part = mSm + (size_t)Bn * Sn * Kn;

    gather_kernel<<<Bn * Sn / 4, 256, 0, stream>>>(masks, feats, indices, fTb, mSm);
    dim3 grid(Sn / BT, Sn / BT, Bn);
    sim_kernel<<<grid, 256, 0, stream>>>(fTb, mSm, part);
    finalize_kernel<<<1, 256, 0, stream>>>(part, out);
}

// Round 7
// 30.897 us; speedup vs baseline: 2.1144x; 1.1482x over previous
//
#include <hip/hip_runtime.h>
#include <hip/hip_bf16.h>
#include <math.h>

#define Bn 2
#define Kn 8
#define Cn 256
#define HWn (128*128)
#define Sn 2048
#define BT 128            // sim block output tile (4 waves, 2x2 of 64x64)
#define BK 64             // k-step staged per LDS buffer
#define NSTEP (Cn / BK)   // 4
#define SIM_BLOCKS ((Sn/BT)*(Sn/BT)*Bn)   // 512

typedef __bf16 bf16x8 __attribute__((ext_vector_type(8)));
typedef float  f32x4  __attribute__((ext_vector_type(4)));

__device__ __forceinline__ void gload_lds16(const ushort* g, ushort* l) {
    __builtin_amdgcn_global_load_lds(
        (const __attribute__((address_space(1))) void*)g,
        (__attribute__((address_space(3))) void*)l,
        16, 0, 0);
}

__device__ __forceinline__ float bf16_to_f32(ushort u) {
    union { unsigned int i; float f; } cv;
    cv.i = ((unsigned int)u) << 16;
    return cv.f;
}

// ---- fast path stage 1: feats (B,C,HW) fp32 -> featsT (B,HW,C) bf16 ----
// 64x64 LDS tile transpose; coalesced 256B reads, 128B-chunk writes.
__global__ __launch_bounds__(256) void transpose_kernel(
    const float* __restrict__ feats, ushort* __restrict__ featsT)
{
    __shared__ float lds[64][65];
    const int b  = blockIdx.z;
    const int C0 = blockIdx.y * 64;
    const int H0 = blockIdx.x * 64;
    const int t  = threadIdx.x;

    const float* base = feats + ((size_t)(b * Cn + C0)) * HWn + H0;
    const int c_l = t >> 4;        // 0..15
    const int h4  = (t & 15) * 4;  // 0..60
    #pragma unroll
    for (int i = 0; i < 4; ++i) {
        const float4 v = *reinterpret_cast<const float4*>(
            base + (size_t)(c_l + 16 * i) * HWn + h4);
        lds[h4 + 0][c_l + 16 * i] = v.x;
        lds[h4 + 1][c_l + 16 * i] = v.y;
        lds[h4 + 2][c_l + 16 * i] = v.z;
        lds[h4 + 3][c_l + 16 * i] = v.w;
    }
    __syncthreads();
    const int h  = t >> 2;          // 0..63
    const int c0 = (t & 3) * 16;    // 0..48
    ushort u[16];
    #pragma unroll
    for (int e = 0; e < 16; ++e) {
        __hip_bfloat16 hv = __float2bfloat16(lds[h][c0 + e]);
        u[e] = *reinterpret_cast<const ushort*>(&hv);
    }
    ushort* dst = featsT + ((size_t)(b * HWn + H0 + h)) * Cn + C0 + c0;
    *reinterpret_cast<uint4*>(dst)     = *reinterpret_cast<const uint4*>(&u[0]);
    *reinterpret_cast<uint4*>(dst + 8) = *reinterpret_cast<const uint4*>(&u[8]);
}

// ---- fast path stage 2: contiguous-row gather + normalize ----
// Wave per sample: 8B/lane coalesced row read, butterfly ||f||^2, write fTb.
__global__ __launch_bounds__(256) void gather2_kernel(
    const float* __restrict__ masks, const ushort* __restrict__ featsT,
    const int* __restrict__ indices, ushort* __restrict__ fTb,
    float* __restrict__ mS)
{
    const int wave = threadIdx.x >> 6;
    const int lane = threadIdx.x & 63;
    const int bs = blockIdx.x * 4 + wave;
    const int b  = bs >> 11;
    const int s  = bs & (Sn - 1);
    const int id = indices[b * Sn + s];

    const ushort4 raw = *reinterpret_cast<const ushort4*>(
        featsT + ((size_t)(b * HWn + id)) * Cn + lane * 4);
    float v[4] = { bf16_to_f32(raw.x), bf16_to_f32(raw.y),
                   bf16_to_f32(raw.z), bf16_to_f32(raw.w) };

    float x = v[0]*v[0] + v[1]*v[1] + v[2]*v[2] + v[3]*v[3];
    #pragma unroll
    for (int o = 32; o > 0; o >>= 1) x += __shfl_xor(x, o);
    const float scale = 1.0f / fmaxf(sqrtf(x), 1e-12f);

    ushort o4[4];
    #pragma unroll
    for (int q = 0; q < 4; ++q) {
        __hip_bfloat16 hv = __float2bfloat16(v[q] * scale);
        o4[q] = *reinterpret_cast<const ushort*>(&hv);
    }
    *reinterpret_cast<ushort4*>(fTb + (size_t)bs * Cn + lane * 4) =
        *reinterpret_cast<const ushort4*>(&o4[0]);

    if (lane < Kn) {
        const float lg = masks[((size_t)(b * Kn + lane)) * HWn + id];
        mS[(size_t)bs * Kn + lane] = 1.0f / (1.0f + expf(-lg));
    }
}

// ---- fallback gather (ws too small): scattered column reads ----
__global__ __launch_bounds__(256) void gather_kernel(
    const float* __restrict__ masks, const float* __restrict__ feats,
    const int* __restrict__ indices, ushort* __restrict__ fTb,
    float* __restrict__ mS)
{
    const int wave = threadIdx.x >> 6;
    const int lane = threadIdx.x & 63;
    const int bs = blockIdx.x * 4 + wave;
    const int b  = bs >> 11;
    const int s  = bs & (Sn - 1);
    const int id = indices[b * Sn + s];

    const float* fb = feats + (size_t)b * Cn * HWn + id;
    float v[4];
    #pragma unroll
    for (int q = 0; q < 4; ++q)
        v[q] = fb[(size_t)(lane + 64 * q) * HWn];

    float x = v[0]*v[0] + v[1]*v[1] + v[2]*v[2] + v[3]*v[3];
    #pragma unroll
    for (int o = 32; o > 0; o >>= 1) x += __shfl_xor(x, o);
    const float scale = 1.0f / fmaxf(sqrtf(x), 1e-12f);

    #pragma unroll
    for (int q = 0; q < 4; ++q) {
        __hip_bfloat16 hv = __float2bfloat16(v[q] * scale);
        fTb[(size_t)bs * Cn + lane + 64 * q] = *reinterpret_cast<const ushort*>(&hv);
    }

    if (lane < Kn) {
        const float lg = masks[((size_t)(b * Kn + lane)) * HWn + id];
        mS[(size_t)bs * Kn + lane] = 1.0f / (1.0f + expf(-lg));
    }
}

// MFMA Gram matrix, m97-structure: global_load_lds double-buffered staging,
// XOR-swizzled. 4 waves (2x2), each 64x64 = 4x4 frags of 16x16x32 bf16.
// Per-block partials -> plain stores (NO atomics).
__global__ __launch_bounds__(256, 2) void sim_kernel(
    const ushort* __restrict__ fTb, const float* __restrict__ mS,
    float* __restrict__ part)
{
    __shared__ ushort ldsA[2][BT * BK];
    __shared__ ushort ldsB[2][BT * BK];

    const int b   = blockIdx.z;
    const int s0  = blockIdx.y * BT;
    const int t0  = blockIdx.x * BT;
    const int tid = threadIdx.x;
    const int lane = tid & 63;
    const int wave = tid >> 6;          // 0..3
    const int wm = wave >> 1, wn = wave & 1;
    const int l15 = lane & 15, l4 = lane >> 4;

    const ushort* FA = fTb + ((size_t)(b * Sn + s0)) * Cn;
    const ushort* FB = fTb + ((size_t)(b * Sn + t0)) * Cn;

    const int qw = wave * 256;
    #define STAGE(buf, k0)                                                     \
    {                                                                          \
        _Pragma("unroll")                                                      \
        for (int i = 0; i < 4; ++i) {                                          \
            const int q   = qw + i * 64 + lane;                                \
            const int row = q >> 3;                                            \
            const int csw = (q & 7) ^ (row & 7);                               \
            const size_t goff = (size_t)row * Cn + (k0) + csw * 8;             \
            gload_lds16(FA + goff, &ldsA[buf][(qw + i * 64) * 8]);             \
            gload_lds16(FB + goff, &ldsB[buf][(qw + i * 64) * 8]);             \
        }                                                                      \
    }

    f32x4 acc[4][4];
    #pragma unroll
    for (int m = 0; m < 4; ++m)
        #pragma unroll
        for (int n = 0; n < 4; ++n) acc[m][n] = (f32x4){0.f, 0.f, 0.f, 0.f};

    STAGE(0, 0);
    __syncthreads();

    #pragma unroll
    for (int s = 0; s < NSTEP; ++s) {
        const int buf = s & 1;
        if (s + 1 < NSTEP) STAGE(buf ^ 1, (s + 1) * BK);

        #pragma unroll
        for (int kk = 0; kk < BK; kk += 32) {
            const int g = (kk >> 3) + l4;
            bf16x8 aF[4], bF[4];
            #pragma unroll
            for (int m = 0; m < 4; ++m) {
                const int row = wm * 64 + m * 16 + l15;
                aF[m] = *reinterpret_cast<const bf16x8*>(
                    &ldsA[buf][row * BK + ((g ^ (row & 7)) << 3)]);
            }
            #pragma unroll
            for (int n = 0; n < 4; ++n) {
                const int row = wn * 64 + n * 16 + l15;
                bF[n] = *reinterpret_cast<const bf16x8*>(
                    &ldsB[buf][row * BK + ((g ^ (row & 7)) << 3)]);
            }
            #pragma unroll
            for (int m = 0; m < 4; ++m)
                #pragma unroll
                for (int n = 0; n < 4; ++n)
                    acc[m][n] = __builtin_amdgcn_mfma_f32_16x16x32_bf16(
                        aF[m], bF[n], acc[m][n], 0, 0, 0);
        }
        __syncthreads();
    }

    // C/D layout: col = lane&15, row = (lane>>4)*4 + reg  [HW-verified m89]
    float num_l = 0.0f, den_l = 0.0f;
    const float* mSb = mS + (size_t)b * Sn * Kn;
    #pragma unroll
    for (int m = 0; m < 4; ++m) {
        #pragma unroll
        for (int n = 0; n < 4; ++n) {
            #pragma unroll
            for (int r = 0; r < 4; ++r) {
                if (acc[m][n][r] > 0.95f) {
                    den_l += 1.0f;
                    const int srow = s0 + wm * 64 + m * 16 + l4 * 4 + r;
                    const int tcol = t0 + wn * 64 + n * 16 + l15;
                    const float* ma = mSb + (size_t)srow * Kn;
                    const float* mb = mSb + (size_t)tcol * Kn;
                    #pragma unroll
                    for (int k = 0; k < Kn; ++k) num_l += fabsf(ma[k] - mb[k]);
                }
            }
        }
    }

    #pragma unroll
    for (int o = 32; o > 0; o >>= 1) {
        num_l += __shfl_down(num_l, o);
        den_l += __shfl_down(den_l, o);
    }
    __shared__ float rn[4], rd[4];
    if (lane == 0) { rn[wave] = num_l; rd[wave] = den_l; }
    __syncthreads();
    if (tid == 0) {
        const int bid = (blockIdx.z * gridDim.y + blockIdx.y) * gridDim.x + blockIdx.x;
        part[2 * bid]     = rn[0] + rn[1] + rn[2] + rn[3];
        part[2 * bid + 1] = rd[0] + rd[1] + rd[2] + rd[3];
    }
}

// Reduce 512 {num,den} pairs and write out = num/(den+eps).
__global__ __launch_bounds__(256) void finalize_kernel(
    const float* __restrict__ part, float* __restrict__ out)
{
    const int tid = threadIdx.x;
    float n = 0.f, d = 0.f;
    #pragma unroll
    for (int i = 0; i < SIM_BLOCKS / 256; ++i) {
        const float2 p = reinterpret_cast<const float2*>(part)[tid + 256 * i];
        n += p.x; d += p.y;
    }
    #pragma unroll
    for (int o = 32; o > 0; o >>= 1) {
        n += __shfl_down(n, o);
        d += __shfl_down(d, o);
    }
    __shared__ float sn[4], sd[4];
    if ((tid & 63) == 0) { sn[tid >> 6] = n; sd[tid >> 6] = d; }
    __syncthreads();
    if (tid == 0) {
        const float fn = sn[0] + sn[1] + sn[2] + sn[3];
        const float fd = sd[0] + sd[1] + sd[2] + sd[3];
        out[0] = fn / (fd + 1e-6f);
    }
}

extern "C" void kernel_launch(void* const* d_in, const int* in_sizes, int n_in,
                              void* d_out, int out_size, void* d_ws, size_t ws_size,
                              hipStream_t stream) {
    const float* masks   = (const float*)d_in[0];   // (B,K,H,W) fp32
    const float* feats   = (const float*)d_in[1];   // (B,C,H,W) fp32
    const int*   indices = (const int*)d_in[2];     // (B,S) int32
    float* out = (float*)d_out;

    // ws: fTb (2MB) | mS (128KB) | part (4KB) | featsT (16MB, fast path only)
    const size_t fTb_b   = (size_t)Bn * Sn * Cn * sizeof(ushort);
    const size_t mS_b    = (size_t)Bn * Sn * Kn * sizeof(float);
    const size_t part_b  = (size_t)SIM_BLOCKS * 2 * sizeof(float);
    const size_t featsT_b = (size_t)Bn * HWn * Cn * sizeof(ushort);

    ushort* fTb   = (ushort*)d_ws;
    float*  mSm   = (float*)((char*)d_ws + fTb_b);
    float*  part  = (float*)((char*)d_ws + fTb_b + mS_b);
    ushort* featsT = (ushort*)((char*)d_ws + fTb_b + mS_b + part_b);

    if (ws_size >= fTb_b + mS_b + part_b + featsT_b) {
        dim3 tg(HWn / 64, Cn / 64, Bn);   // (256, 4, 2)
        transpose_kernel<<<tg, 256, 0, stream>>>(feats, featsT);
        gather2_kernel<<<Bn * Sn / 4, 256, 0, stream>>>(masks, featsT, indices, fTb, mSm);
    } else {
        gather_kernel<<<Bn * Sn / 4, 256, 0, stream>>>(masks, feats, indices, fTb, mSm);
    }
    dim3 grid(Sn / BT, Sn / BT, Bn);
    sim_kernel<<<grid, 256, 0, stream>>>(fTb, mSm, part);
    finalize_kernel<<<1, 256, 0, stream>>>(part, out);
}

// Round 8
// 29.135 us; speedup vs baseline: 2.2422x; 1.0605x over previous
//
#include <hip/hip_runtime.h>
#include <hip/hip_bf16.h>
#include <math.h>

#define Bn 2
#define Kn 8
#define Cn 256
#define HWn (128*128)
#define Sn 2048
#define BT 128            // sim block output tile (8 waves, 2x4 of 64x32)
#define BK 64             // k-step staged per LDS buffer
#define NSTEP (Cn / BK)   // 4
#define SIM_BLOCKS ((Sn/BT)*(Sn/BT)*Bn)   // 512

typedef __bf16 bf16x8 __attribute__((ext_vector_type(8)));
typedef float  f32x4  __attribute__((ext_vector_type(4)));

__device__ __forceinline__ void gload_lds16(const ushort* g, ushort* l) {
    __builtin_amdgcn_global_load_lds(
        (const __attribute__((address_space(1))) void*)g,
        (__attribute__((address_space(3))) void*)l,
        16, 0, 0);
}

__device__ __forceinline__ float bf16_to_f32(ushort u) {
    union { unsigned int i; float f; } cv;
    cv.i = ((unsigned int)u) << 16;
    return cv.f;
}

// ---- stage 1: feats (B,C,HW) fp32 -> featsT (B,HW,C) bf16 ----
__global__ __launch_bounds__(256) void transpose_kernel(
    const float* __restrict__ feats, ushort* __restrict__ featsT)
{
    __shared__ float lds[64][65];
    const int b  = blockIdx.z;
    const int C0 = blockIdx.y * 64;
    const int H0 = blockIdx.x * 64;
    const int t  = threadIdx.x;

    const float* base = feats + ((size_t)(b * Cn + C0)) * HWn + H0;
    const int c_l = t >> 4;        // 0..15
    const int h4  = (t & 15) * 4;  // 0..60
    #pragma unroll
    for (int i = 0; i < 4; ++i) {
        const float4 v = *reinterpret_cast<const float4*>(
            base + (size_t)(c_l + 16 * i) * HWn + h4);
        lds[h4 + 0][c_l + 16 * i] = v.x;
        lds[h4 + 1][c_l + 16 * i] = v.y;
        lds[h4 + 2][c_l + 16 * i] = v.z;
        lds[h4 + 3][c_l + 16 * i] = v.w;
    }
    __syncthreads();
    const int h  = t >> 2;          // 0..63
    const int c0 = (t & 3) * 16;    // 0..48
    ushort u[16];
    #pragma unroll
    for (int e = 0; e < 16; ++e) {
        __hip_bfloat16 hv = __float2bfloat16(lds[h][c0 + e]);
        u[e] = *reinterpret_cast<const ushort*>(&hv);
    }
    ushort* dst = featsT + ((size_t)(b * HWn + H0 + h)) * Cn + C0 + c0;
    *reinterpret_cast<uint4*>(dst)     = *reinterpret_cast<const uint4*>(&u[0]);
    *reinterpret_cast<uint4*>(dst + 8) = *reinterpret_cast<const uint4*>(&u[8]);
}

// ---- stage 2: contiguous-row gather + normalize ----
__global__ __launch_bounds__(256) void gather2_kernel(
    const float* __restrict__ masks, const ushort* __restrict__ featsT,
    const int* __restrict__ indices, ushort* __restrict__ fTb,
    float* __restrict__ mS)
{
    const int wave = threadIdx.x >> 6;
    const int lane = threadIdx.x & 63;
    const int bs = blockIdx.x * 4 + wave;
    const int b  = bs >> 11;
    const int s  = bs & (Sn - 1);
    const int id = indices[b * Sn + s];

    const ushort4 raw = *reinterpret_cast<const ushort4*>(
        featsT + ((size_t)(b * HWn + id)) * Cn + lane * 4);
    float v[4] = { bf16_to_f32(raw.x), bf16_to_f32(raw.y),
                   bf16_to_f32(raw.z), bf16_to_f32(raw.w) };

    float x = v[0]*v[0] + v[1]*v[1] + v[2]*v[2] + v[3]*v[3];
    #pragma unroll
    for (int o = 32; o > 0; o >>= 1) x += __shfl_xor(x, o);
    const float scale = 1.0f / fmaxf(sqrtf(x), 1e-12f);

    ushort o4[4];
    #pragma unroll
    for (int q = 0; q < 4; ++q) {
        __hip_bfloat16 hv = __float2bfloat16(v[q] * scale);
        o4[q] = *reinterpret_cast<const ushort*>(&hv);
    }
    *reinterpret_cast<ushort4*>(fTb + (size_t)bs * Cn + lane * 4) =
        *reinterpret_cast<const ushort4*>(&o4[0]);

    if (lane < Kn) {
        const float lg = masks[((size_t)(b * Kn + lane)) * HWn + id];
        mS[(size_t)bs * Kn + lane] = 1.0f / (1.0f + expf(-lg));
    }
}

// ---- fallback gather (ws too small): scattered column reads ----
__global__ __launch_bounds__(256) void gather_kernel(
    const float* __restrict__ masks, const float* __restrict__ feats,
    const int* __restrict__ indices, ushort* __restrict__ fTb,
    float* __restrict__ mS)
{
    const int wave = threadIdx.x >> 6;
    const int lane = threadIdx.x & 63;
    const int bs = blockIdx.x * 4 + wave;
    const int b  = bs >> 11;
    const int s  = bs & (Sn - 1);
    const int id = indices[b * Sn + s];

    const float* fb = feats + (size_t)b * Cn * HWn + id;
    float v[4];
    #pragma unroll
    for (int q = 0; q < 4; ++q)
        v[q] = fb[(size_t)(lane + 64 * q) * HWn];

    float x = v[0]*v[0] + v[1]*v[1] + v[2]*v[2] + v[3]*v[3];
    #pragma unroll
    for (int o = 32; o > 0; o >>= 1) x += __shfl_xor(x, o);
    const float scale = 1.0f / fmaxf(sqrtf(x), 1e-12f);

    #pragma unroll
    for (int q = 0; q < 4; ++q) {
        __hip_bfloat16 hv = __float2bfloat16(v[q] * scale);
        fTb[(size_t)bs * Cn + lane + 64 * q] = *reinterpret_cast<const ushort*>(&hv);
    }

    if (lane < Kn) {
        const float lg = masks[((size_t)(b * Kn + lane)) * HWn + id];
        mS[(size_t)bs * Kn + lane] = 1.0f / (1.0f + expf(-lg));
    }
}

// MFMA Gram matrix: 512 threads = 8 waves (2x4), wave tile 64x32 (4x2 frags
// of 16x16x32 bf16). global_load_lds double-buffered, involution-swizzled.
// 2 blocks/CU = 16 waves/CU for barrier-drain overlap. Plain-store partials.
__global__ __launch_bounds__(512, 4) void sim_kernel(
    const ushort* __restrict__ fTb, const float* __restrict__ mS,
    float* __restrict__ part)
{
    __shared__ ushort ldsA[2][BT * BK];
    __shared__ ushort ldsB[2][BT * BK];

    const int b   = blockIdx.z;
    const int s0  = blockIdx.y * BT;
    const int t0  = blockIdx.x * BT;
    const int tid = threadIdx.x;
    const int lane = tid & 63;
    const int wave = tid >> 6;          // 0..7
    const int wm = wave >> 2;           // 0..1 : 64-row slab
    const int wn = wave & 3;            // 0..3 : 32-col slab
    const int l15 = lane & 15, l4 = lane >> 4;

    const ushort* FA = fTb + ((size_t)(b * Sn + s0)) * Cn;
    const ushort* FB = fTb + ((size_t)(b * Sn + t0)) * Cn;

    // staging: each matrix tile = 1024 chunks of 16B; 512 threads x 2 chunks.
    // LDS slot (row, c) receives global chunk (c ^ (row&7))  [involution]
    #define STAGE(buf, k0)                                                     \
    {                                                                          \
        _Pragma("unroll")                                                      \
        for (int i = 0; i < 2; ++i) {                                          \
            const int q   = tid + i * 512;                                     \
            const int row = q >> 3;                                            \
            const int csw = (q & 7) ^ (row & 7);                               \
            const size_t goff = (size_t)row * Cn + (k0) + csw * 8;             \
            gload_lds16(FA + goff, &ldsA[buf][q * 8]);                         \
            gload_lds16(FB + goff, &ldsB[buf][q * 8]);                         \
        }                                                                      \
    }

    f32x4 acc[4][2];
    #pragma unroll
    for (int m = 0; m < 4; ++m)
        #pragma unroll
        for (int n = 0; n < 2; ++n) acc[m][n] = (f32x4){0.f, 0.f, 0.f, 0.f};

    STAGE(0, 0);
    __syncthreads();

    #pragma unroll
    for (int s = 0; s < NSTEP; ++s) {
        const int buf = s & 1;
        if (s + 1 < NSTEP) STAGE(buf ^ 1, (s + 1) * BK);

        #pragma unroll
        for (int kk = 0; kk < BK; kk += 32) {
            const int g = (kk >> 3) + l4;           // chunk 0..7
            bf16x8 aF[4], bF[2];
            #pragma unroll
            for (int m = 0; m < 4; ++m) {
                const int row = wm * 64 + m * 16 + l15;
                aF[m] = *reinterpret_cast<const bf16x8*>(
                    &ldsA[buf][row * BK + ((g ^ (row & 7)) << 3)]);
            }
            #pragma unroll
            for (int n = 0; n < 2; ++n) {
                const int row = wn * 32 + n * 16 + l15;
                bF[n] = *reinterpret_cast<const bf16x8*>(
                    &ldsB[buf][row * BK + ((g ^ (row & 7)) << 3)]);
            }
            #pragma unroll
            for (int m = 0; m < 4; ++m)
                #pragma unroll
                for (int n = 0; n < 2; ++n)
                    acc[m][n] = __builtin_amdgcn_mfma_f32_16x16x32_bf16(
                        aF[m], bF[n], acc[m][n], 0, 0, 0);
        }
        __syncthreads();
    }

    // C/D layout: col = lane&15, row = (lane>>4)*4 + reg  [HW-verified m89]
    float num_l = 0.0f, den_l = 0.0f;
    const float* mSb = mS + (size_t)b * Sn * Kn;
    #pragma unroll
    for (int m = 0; m < 4; ++m) {
        #pragma unroll
        for (int n = 0; n < 2; ++n) {
            #pragma unroll
            for (int r = 0; r < 4; ++r) {
                if (acc[m][n][r] > 0.95f) {
                    den_l += 1.0f;
                    const int srow = s0 + wm * 64 + m * 16 + l4 * 4 + r;
                    const int tcol = t0 + wn * 32 + n * 16 + l15;
                    const float* ma = mSb + (size_t)srow * Kn;
                    const float* mb = mSb + (size_t)tcol * Kn;
                    #pragma unroll
                    for (int k = 0; k < Kn; ++k) num_l += fabsf(ma[k] - mb[k]);
                }
            }
        }
    }

    #pragma unroll
    for (int o = 32; o > 0; o >>= 1) {
        num_l += __shfl_down(num_l, o);
        den_l += __shfl_down(den_l, o);
    }
    __shared__ float rn[8], rd[8];
    if (lane == 0) { rn[wave] = num_l; rd[wave] = den_l; }
    __syncthreads();
    if (tid == 0) {
        float nn = 0.f, dd = 0.f;
        #pragma unroll
        for (int w = 0; w < 8; ++w) { nn += rn[w]; dd += rd[w]; }
        const int bid = (blockIdx.z * gridDim.y + blockIdx.y) * gridDim.x + blockIdx.x;
        part[2 * bid]     = nn;
        part[2 * bid + 1] = dd;
    }
}

// Reduce 512 {num,den} pairs and write out = num/(den+eps).
__global__ __launch_bounds__(256) void finalize_kernel(
    const float* __restrict__ part, float* __restrict__ out)
{
    const int tid = threadIdx.x;
    float n = 0.f, d = 0.f;
    #pragma unroll
    for (int i = 0; i < SIM_BLOCKS / 256; ++i) {
        const float2 p = reinterpret_cast<const float2*>(part)[tid + 256 * i];
        n += p.x; d += p.y;
    }
    #pragma unroll
    for (int o = 32; o > 0; o >>= 1) {
        n += __shfl_down(n, o);
        d += __shfl_down(d, o);
    }
    __shared__ float sn[4], sd[4];
    if ((tid & 63) == 0) { sn[tid >> 6] = n; sd[tid >> 6] = d; }
    __syncthreads();
    if (tid == 0) {
        const float fn = sn[0] + sn[1] + sn[2] + sn[3];
        const float fd = sd[0] + sd[1] + sd[2] + sd[3];
        out[0] = fn / (fd + 1e-6f);
    }
}

extern "C" void kernel_launch(void* const* d_in, const int* in_sizes, int n_in,
                              void* d_out, int out_size, void* d_ws, size_t ws_size,
                              hipStream_t stream) {
    const float* masks   = (const float*)d_in[0];   // (B,K,H,W) fp32
    const float* feats   = (const float*)d_in[1];   // (B,C,H,W) fp32
    const int*   indices = (const int*)d_in[2];     // (B,S) int32
    float* out = (float*)d_out;

    // ws: fTb (2MB) | mS (128KB) | part (4KB) | featsT (16MB, fast path only)
    const size_t fTb_b   = (size_t)Bn * Sn * Cn * sizeof(ushort);
    const size_t mS_b    = (size_t)Bn * Sn * Kn * sizeof(float);
    const size_t part_b  = (size_t)SIM_BLOCKS * 2 * sizeof(float);
    const size_t featsT_b = (size_t)Bn * HWn * Cn * sizeof(ushort);

    ushort* fTb   = (ushort*)d_ws;
    float*  mSm   = (float*)((char*)d_ws + fTb_b);
    float*  part  = (float*)((char*)d_ws + fTb_b + mS_b);
    ushort* featsT = (ushort*)((char*)d_ws + fTb_b + mS_b + part_b);

    if (ws_size >= fTb_b + mS_b + part_b + featsT_b) {
        dim3 tg(HWn / 64, Cn / 64, Bn);   // (256, 4, 2)
        transpose_kernel<<<tg, 256, 0, stream>>>(feats, featsT);
        gather2_kernel<<<Bn * Sn / 4, 256, 0, stream>>>(masks, featsT, indices, fTb, mSm);
    } else {
        gather_kernel<<<Bn * Sn / 4, 256, 0, stream>>>(masks, feats, indices, fTb, mSm);
    }
    dim3 grid(Sn / BT, Sn / BT, Bn);
    sim_kernel<<<grid, 512, 0, stream>>>(fTb, mSm, part);
    finalize_kernel<<<1, 256, 0, stream>>>(part, out);
}

// Round 9
// 28.155 us; speedup vs baseline: 2.3203x; 1.0348x over previous
//
#include <hip/hip_runtime.h>
#include <hip/hip_bf16.h>
#include <math.h>

#define Bn 2
#define Kn 8
#define Cn 256
#define HWn (128*128)
#define Sn 2048
#define BT 128            // sim block output tile (8 waves, 2x4 of 64x32)
#define BKc 128           // k-slice width (ushorts) staged per LDS fill
#define NSTAGE (Cn / BKc) // 2
#define SIM_BLOCKS ((Sn/BT)*(Sn/BT)*Bn)   // 512

typedef __bf16 bf16x8 __attribute__((ext_vector_type(8)));
typedef float  f32x4  __attribute__((ext_vector_type(4)));

__device__ __forceinline__ void gload_lds16(const ushort* g, ushort* l) {
    __builtin_amdgcn_global_load_lds(
        (const __attribute__((address_space(1))) void*)g,
        (__attribute__((address_space(3))) void*)l,
        16, 0, 0);
}

__device__ __forceinline__ float bf16_to_f32(ushort u) {
    union { unsigned int i; float f; } cv;
    cv.i = ((unsigned int)u) << 16;
    return cv.f;
}

// ---- stage 1: feats (B,C,HW) fp32 -> featsT (B,HW,C) bf16 ----
__global__ __launch_bounds__(256) void transpose_kernel(
    const float* __restrict__ feats, ushort* __restrict__ featsT)
{
    __shared__ float lds[64][65];
    const int b  = blockIdx.z;
    const int C0 = blockIdx.y * 64;
    const int H0 = blockIdx.x * 64;
    const int t  = threadIdx.x;

    const float* base = feats + ((size_t)(b * Cn + C0)) * HWn + H0;
    const int c_l = t >> 4;        // 0..15
    const int h4  = (t & 15) * 4;  // 0..60
    #pragma unroll
    for (int i = 0; i < 4; ++i) {
        const float4 v = *reinterpret_cast<const float4*>(
            base + (size_t)(c_l + 16 * i) * HWn + h4);
        lds[h4 + 0][c_l + 16 * i] = v.x;
        lds[h4 + 1][c_l + 16 * i] = v.y;
        lds[h4 + 2][c_l + 16 * i] = v.z;
        lds[h4 + 3][c_l + 16 * i] = v.w;
    }
    __syncthreads();
    const int h  = t >> 2;          // 0..63
    const int c0 = (t & 3) * 16;    // 0..48
    ushort u[16];
    #pragma unroll
    for (int e = 0; e < 16; ++e) {
        __hip_bfloat16 hv = __float2bfloat16(lds[h][c0 + e]);
        u[e] = *reinterpret_cast<const ushort*>(&hv);
    }
    ushort* dst = featsT + ((size_t)(b * HWn + H0 + h)) * Cn + C0 + c0;
    *reinterpret_cast<uint4*>(dst)     = *reinterpret_cast<const uint4*>(&u[0]);
    *reinterpret_cast<uint4*>(dst + 8) = *reinterpret_cast<const uint4*>(&u[8]);
}

// ---- stage 2: contiguous-row gather + normalize ----
__global__ __launch_bounds__(256) void gather2_kernel(
    const float* __restrict__ masks, const ushort* __restrict__ featsT,
    const int* __restrict__ indices, ushort* __restrict__ fTb,
    float* __restrict__ mS)
{
    const int wave = threadIdx.x >> 6;
    const int lane = threadIdx.x & 63;
    const int bs = blockIdx.x * 4 + wave;
    const int b  = bs >> 11;
    const int s  = bs & (Sn - 1);
    const int id = indices[b * Sn + s];

    const ushort4 raw = *reinterpret_cast<const ushort4*>(
        featsT + ((size_t)(b * HWn + id)) * Cn + lane * 4);
    float v[4] = { bf16_to_f32(raw.x), bf16_to_f32(raw.y),
                   bf16_to_f32(raw.z), bf16_to_f32(raw.w) };

    float x = v[0]*v[0] + v[1]*v[1] + v[2]*v[2] + v[3]*v[3];
    #pragma unroll
    for (int o = 32; o > 0; o >>= 1) x += __shfl_xor(x, o);
    const float scale = 1.0f / fmaxf(sqrtf(x), 1e-12f);

    ushort o4[4];
    #pragma unroll
    for (int q = 0; q < 4; ++q) {
        __hip_bfloat16 hv = __float2bfloat16(v[q] * scale);
        o4[q] = *reinterpret_cast<const ushort*>(&hv);
    }
    *reinterpret_cast<ushort4*>(fTb + (size_t)bs * Cn + lane * 4) =
        *reinterpret_cast<const ushort4*>(&o4[0]);

    if (lane < Kn) {
        const float lg = masks[((size_t)(b * Kn + lane)) * HWn + id];
        mS[(size_t)bs * Kn + lane] = 1.0f / (1.0f + expf(-lg));
    }
}

// ---- fallback gather (ws too small): scattered column reads ----
__global__ __launch_bounds__(256) void gather_kernel(
    const float* __restrict__ masks, const float* __restrict__ feats,
    const int* __restrict__ indices, ushort* __restrict__ fTb,
    float* __restrict__ mS)
{
    const int wave = threadIdx.x >> 6;
    const int lane = threadIdx.x & 63;
    const int bs = blockIdx.x * 4 + wave;
    const int b  = bs >> 11;
    const int s  = bs & (Sn - 1);
    const int id = indices[b * Sn + s];

    const float* fb = feats + (size_t)b * Cn * HWn + id;
    float v[4];
    #pragma unroll
    for (int q = 0; q < 4; ++q)
        v[q] = fb[(size_t)(lane + 64 * q) * HWn];

    float x = v[0]*v[0] + v[1]*v[1] + v[2]*v[2] + v[3]*v[3];
    #pragma unroll
    for (int o = 32; o > 0; o >>= 1) x += __shfl_xor(x, o);
    const float scale = 1.0f / fmaxf(sqrtf(x), 1e-12f);

    #pragma unroll
    for (int q = 0; q < 4; ++q) {
        __hip_bfloat16 hv = __float2bfloat16(v[q] * scale);
        fTb[(size_t)bs * Cn + lane + 64 * q] = *reinterpret_cast<const ushort*>(&hv);
    }

    if (lane < Kn) {
        const float lg = masks[((size_t)(b * Kn + lane)) * HWn + id];
        mS[(size_t)bs * Kn + lane] = 1.0f / (1.0f + expf(-lg));
    }
}

// MFMA Gram matrix: single-buffered BK=128 staging (2 stages, 1 barrier each,
// 8 loads/thread in flight per stage). 8 waves (2x4), wave tile 64x32.
// 64 KB LDS -> 2 blocks/CU; co-resident blocks overlap stage/compute phases.
__global__ __launch_bounds__(512, 4) void sim_kernel(
    const ushort* __restrict__ fTb, const float* __restrict__ mS,
    float* __restrict__ part)
{
    __shared__ ushort ldsA[BT * BKc];   // 32 KB
    __shared__ ushort ldsB[BT * BKc];   // 32 KB

    const int b   = blockIdx.z;
    const int s0  = blockIdx.y * BT;
    const int t0  = blockIdx.x * BT;
    const int tid = threadIdx.x;
    const int lane = tid & 63;
    const int wave = tid >> 6;          // 0..7
    const int wm = wave >> 2;           // 0..1 : 64-row slab
    const int wn = wave & 3;            // 0..3 : 32-col slab
    const int l15 = lane & 15, l4 = lane >> 4;

    const ushort* FA = fTb + ((size_t)(b * Sn + s0)) * Cn;
    const ushort* FB = fTb + ((size_t)(b * Sn + t0)) * Cn;

    f32x4 acc[4][2];
    #pragma unroll
    for (int m = 0; m < 4; ++m)
        #pragma unroll
        for (int n = 0; n < 2; ++n) acc[m][n] = (f32x4){0.f, 0.f, 0.f, 0.f};

    #pragma unroll
    for (int st = 0; st < NSTAGE; ++st) {
        const int k0 = st * BKc;
        // stage: 2048 16B-chunks per matrix; 512 threads x 4; involution
        // swizzle over 16 chunks/row: LDS slot (row,c) <- global (c^(row&15))
        #pragma unroll
        for (int i = 0; i < 4; ++i) {
            const int q   = tid + i * 512;          // 0..2047
            const int row = q >> 4;                 // 0..127
            const int csw = (q & 15) ^ (row & 15);
            const size_t goff = (size_t)row * Cn + k0 + csw * 8;
            gload_lds16(FA + goff, &ldsA[q * 8]);
            gload_lds16(FB + goff, &ldsB[q * 8]);
        }
        __syncthreads();   // drains vmcnt once per stage

        #pragma unroll
        for (int kk = 0; kk < BKc; kk += 32) {
            const int g = (kk >> 3) + l4;           // chunk 0..15
            bf16x8 aF[4], bF[2];
            #pragma unroll
            for (int m = 0; m < 4; ++m) {
                const int row = wm * 64 + m * 16 + l15;
                aF[m] = *reinterpret_cast<const bf16x8*>(
                    &ldsA[row * BKc + ((g ^ (row & 15)) << 3)]);
            }
            #pragma unroll
            for (int n = 0; n < 2; ++n) {
                const int row = wn * 32 + n * 16 + l15;
                bF[n] = *reinterpret_cast<const bf16x8*>(
                    &ldsB[row * BKc + ((g ^ (row & 15)) << 3)]);
            }
            #pragma unroll
            for (int m = 0; m < 4; ++m)
                #pragma unroll
                for (int n = 0; n < 2; ++n)
                    acc[m][n] = __builtin_amdgcn_mfma_f32_16x16x32_bf16(
                        aF[m], bF[n], acc[m][n], 0, 0, 0);
        }
        __syncthreads();   // LDS consumed before next stage overwrites
    }

    // C/D layout: col = lane&15, row = (lane>>4)*4 + reg  [HW-verified m89]
    float num_l = 0.0f, den_l = 0.0f;
    const float* mSb = mS + (size_t)b * Sn * Kn;
    #pragma unroll
    for (int m = 0; m < 4; ++m) {
        #pragma unroll
        for (int n = 0; n < 2; ++n) {
            #pragma unroll
            for (int r = 0; r < 4; ++r) {
                if (acc[m][n][r] > 0.95f) {
                    den_l += 1.0f;
                    const int srow = s0 + wm * 64 + m * 16 + l4 * 4 + r;
                    const int tcol = t0 + wn * 32 + n * 16 + l15;
                    const float* ma = mSb + (size_t)srow * Kn;
                    const float* mb = mSb + (size_t)tcol * Kn;
                    #pragma unroll
                    for (int k = 0; k < Kn; ++k) num_l += fabsf(ma[k] - mb[k]);
                }
            }
        }
    }

    #pragma unroll
    for (int o = 32; o > 0; o >>= 1) {
        num_l += __shfl_down(num_l, o);
        den_l += __shfl_down(den_l, o);
    }
    __shared__ float rn[8], rd[8];
    if (lane == 0) { rn[wave] = num_l; rd[wave] = den_l; }
    __syncthreads();
    if (tid == 0) {
        float nn = 0.f, dd = 0.f;
        #pragma unroll
        for (int w = 0; w < 8; ++w) { nn += rn[w]; dd += rd[w]; }
        const int bid = (blockIdx.z * gridDim.y + blockIdx.y) * gridDim.x + blockIdx.x;
        part[2 * bid]     = nn;
        part[2 * bid + 1] = dd;
    }
}

// Reduce 512 {num,den} pairs and write out = num/(den+eps).
__global__ __launch_bounds__(256) void finalize_kernel(
    const float* __restrict__ part, float* __restrict__ out)
{
    const int tid = threadIdx.x;
    float n = 0.f, d = 0.f;
    #pragma unroll
    for (int i = 0; i < SIM_BLOCKS / 256; ++i) {
        const float2 p = reinterpret_cast<const float2*>(part)[tid + 256 * i];
        n += p.x; d += p.y;
    }
    #pragma unroll
    for (int o = 32; o > 0; o >>= 1) {
        n += __shfl_down(n, o);
        d += __shfl_down(d, o);
    }
    __shared__ float sn[4], sd[4];
    if ((tid & 63) == 0) { sn[tid >> 6] = n; sd[tid >> 6] = d; }
    __syncthreads();
    if (tid == 0) {
        const float fn = sn[0] + sn[1] + sn[2] + sn[3];
        const float fd = sd[0] + sd[1] + sd[2] + sd[3];
        out[0] = fn / (fd + 1e-6f);
    }
}

extern "C" void kernel_launch(void* const* d_in, const int* in_sizes, int n_in,
                              void* d_out, int out_size, void* d_ws, size_t ws_size,
                              hipStream_t stream) {
    const float* masks   = (const float*)d_in[0];   // (B,K,H,W) fp32
    const float* feats   = (const float*)d_in[1];   // (B,C,H,W) fp32
    const int*   indices = (const int*)d_in[2];     // (B,S) int32
    float* out = (float*)d_out;

    // ws: fTb (2MB) | mS (128KB) | part (4KB) | featsT (16MB, fast path only)
    const size_t fTb_b   = (size_t)Bn * Sn * Cn * sizeof(ushort);
    const size_t mS_b    = (size_t)Bn * Sn * Kn * sizeof(float);
    const size_t part_b  = (size_t)SIM_BLOCKS * 2 * sizeof(float);
    const size_t featsT_b = (size_t)Bn * HWn * Cn * sizeof(ushort);

    ushort* fTb   = (ushort*)d_ws;
    float*  mSm   = (float*)((char*)d_ws + fTb_b);
    float*  part  = (float*)((char*)d_ws + fTb_b + mS_b);
    ushort* featsT = (ushort*)((char*)d_ws + fTb_b + mS_b + part_b);

    if (ws_size >= fTb_b + mS_b + part_b + featsT_b) {
        dim3 tg(HWn / 64, Cn / 64, Bn);   // (256, 4, 2)
        transpose_kernel<<<tg, 256, 0, stream>>>(feats, featsT);
        gather2_kernel<<<Bn * Sn / 4, 256, 0, stream>>>(masks, featsT, indices, fTb, mSm);
    } else {
        gather_kernel<<<Bn * Sn / 4, 256, 0, stream>>>(masks, feats, indices, fTb, mSm);
    }
    dim3 grid(Sn / BT, Sn / BT, Bn);
    sim_kernel<<<grid, 512, 0, stream>>>(fTb, mSm, part);
    finalize_kernel<<<1, 256, 0, stream>>>(part, out);
}

// Round 10
// 27.824 us; speedup vs baseline: 2.3479x; 1.0119x over previous
//
#include <hip/hip_runtime.h>
#include <hip/hip_bf16.h>
#include <math.h>

#define Bn 2
#define Kn 8
#define Cn 256
#define HWn (128*128)
#define Sn 2048
#define BT 128            // sim block output tile (8 waves, 2x4 of 64x32)
#define BKc 128           // k-slice width (ushorts) staged per LDS fill
#define NSTAGE (Cn / BKc) // 2
#define NT (Sn / BT)      // 16 tile-rows
#define NTRI (NT*(NT+1)/2)   // 136 upper-triangle blocks per batch
#define NPART (NTRI * Bn)    // 272
#define TLH 64            // gatherT h-tile width

typedef __bf16 bf16x8 __attribute__((ext_vector_type(8)));
typedef float  f32x4  __attribute__((ext_vector_type(4)));

__device__ __forceinline__ void gload_lds16(const ushort* g, ushort* l) {
    __builtin_amdgcn_global_load_lds(
        (const __attribute__((address_space(1))) void*)g,
        (__attribute__((address_space(3))) void*)l,
        16, 0, 0);
}

__device__ __forceinline__ float bf16_to_f32(ushort u) {
    union { unsigned int i; float f; } cv;
    cv.i = ((unsigned int)u) << 16;
    return cv.f;
}
__device__ __forceinline__ ushort f32_to_bf16u(float f) {
    __hip_bfloat16 hv = __float2bfloat16(f);
    return *reinterpret_cast<const ushort*>(&hv);
}

// ---- fused gather: stream feats coalesced, keep only sampled columns ----
// One block per (b, 64-wide h-tile): LDS-stage [256 c][64 h] as bf16,
// find sampled h via index scan, normalize + write fTb row + sigmoid masks.
__global__ __launch_bounds__(256) void gatherT_kernel(
    const float* __restrict__ masks, const float* __restrict__ feats,
    const int* __restrict__ indices, ushort* __restrict__ fTb,
    float* __restrict__ mS)
{
    __shared__ ushort tile[Cn][TLH + 4];   // stride 68 ushorts (136 B)
    __shared__ int smap[TLH];

    const int b  = blockIdx.y;
    const int h0 = blockIdx.x * TLH;
    const int t  = threadIdx.x;
    const int lane = t & 63;
    const int wave = t >> 6;

    if (t < TLH) smap[t] = -1;
    __syncthreads();

    // membership scan: 2048 indices, 8 per thread (permutation -> no races)
    #pragma unroll
    for (int i = 0; i < 8; ++i) {
        const int s  = t * 8 + i;
        const int d  = indices[b * Sn + s] - h0;
        if ((unsigned)d < TLH) smap[d] = s;
    }

    // coalesced tile load: c = (t>>4)+16*it, h4 = (t&15)*4
    const float* fb = feats + ((size_t)b * Cn) * HWn + h0;
    const int c_l = t >> 4;
    const int h4  = (t & 15) * 4;
    #pragma unroll
    for (int it = 0; it < 16; ++it) {
        const int c = c_l + 16 * it;
        const float4 v = *reinterpret_cast<const float4*>(fb + (size_t)c * HWn + h4);
        ushort4 u;
        u.x = f32_to_bf16u(v.x); u.y = f32_to_bf16u(v.y);
        u.z = f32_to_bf16u(v.z); u.w = f32_to_bf16u(v.w);
        *reinterpret_cast<ushort4*>(&tile[c][h4]) = u;
    }
    __syncthreads();

    // wave per sampled column (strided over slots; branch wave-uniform)
    for (int hs = wave; hs < TLH; hs += 4) {
        const int p = smap[hs];
        if (p < 0) continue;
        float v[4];
        #pragma unroll
        for (int q = 0; q < 4; ++q)
            v[q] = bf16_to_f32(tile[lane + 64 * q][hs]);
        float x = v[0]*v[0] + v[1]*v[1] + v[2]*v[2] + v[3]*v[3];
        #pragma unroll
        for (int o = 32; o > 0; o >>= 1) x += __shfl_xor(x, o);
        const float scale = 1.0f / fmaxf(sqrtf(x), 1e-12f);
        #pragma unroll
        for (int q = 0; q < 4; ++q)
            fTb[(size_t)(b * Sn + p) * Cn + lane + 64 * q] =
                f32_to_bf16u(v[q] * scale);
        if (lane < Kn) {
            const float lg = masks[((size_t)(b * Kn + lane)) * HWn + h0 + hs];
            mS[(size_t)(b * Sn + p) * Kn + lane] = 1.0f / (1.0f + expf(-lg));
        }
    }
}

// MFMA Gram matrix over UPPER-TRIANGLE tile pairs only (sim symmetric;
// diagonal contributes 0 to num, exactly B*S to den). Single-buffered
// BK=128 staging, 8 waves (2x4) of 64x32, involution swizzle. Plain stores.
__global__ __launch_bounds__(512, 4) void sim_kernel(
    const ushort* __restrict__ fTb, const float* __restrict__ mS,
    float* __restrict__ part)
{
    __shared__ ushort ldsA[BT * BKc];   // 32 KB
    __shared__ ushort ldsB[BT * BKc];   // 32 KB

    const int b = blockIdx.y;
    // decode upper-triangle pair (i <= j) from blockIdx.x
    int i = 0, rem = blockIdx.x;
    while (rem >= NT - i) { rem -= NT - i; ++i; }
    const int j  = i + rem;
    const int s0 = i * BT;
    const int t0 = j * BT;

    const int tid = threadIdx.x;
    const int lane = tid & 63;
    const int wave = tid >> 6;          // 0..7
    const int wm = wave >> 2;           // 0..1 : 64-row slab
    const int wn = wave & 3;            // 0..3 : 32-col slab
    const int l15 = lane & 15, l4 = lane >> 4;

    const ushort* FA = fTb + ((size_t)(b * Sn + s0)) * Cn;
    const ushort* FB = fTb + ((size_t)(b * Sn + t0)) * Cn;

    f32x4 acc[4][2];
    #pragma unroll
    for (int m = 0; m < 4; ++m)
        #pragma unroll
        for (int n = 0; n < 2; ++n) acc[m][n] = (f32x4){0.f, 0.f, 0.f, 0.f};

    #pragma unroll
    for (int st = 0; st < NSTAGE; ++st) {
        const int k0 = st * BKc;
        // stage: 2048 16B-chunks/matrix; involution swizzle over 16 chunks/row
        #pragma unroll
        for (int i2 = 0; i2 < 4; ++i2) {
            const int q   = tid + i2 * 512;
            const int row = q >> 4;
            const int csw = (q & 15) ^ (row & 15);
            const size_t goff = (size_t)row * Cn + k0 + csw * 8;
            gload_lds16(FA + goff, &ldsA[q * 8]);
            gload_lds16(FB + goff, &ldsB[q * 8]);
        }
        __syncthreads();

        #pragma unroll
        for (int kk = 0; kk < BKc; kk += 32) {
            const int g = (kk >> 3) + l4;
            bf16x8 aF[4], bF[2];
            #pragma unroll
            for (int m = 0; m < 4; ++m) {
                const int row = wm * 64 + m * 16 + l15;
                aF[m] = *reinterpret_cast<const bf16x8*>(
                    &ldsA[row * BKc + ((g ^ (row & 15)) << 3)]);
            }
            #pragma unroll
            for (int n = 0; n < 2; ++n) {
                const int row = wn * 32 + n * 16 + l15;
                bF[n] = *reinterpret_cast<const bf16x8*>(
                    &ldsB[row * BKc + ((g ^ (row & 15)) << 3)]);
            }
            #pragma unroll
            for (int m = 0; m < 4; ++m)
                #pragma unroll
                for (int n = 0; n < 2; ++n)
                    acc[m][n] = __builtin_amdgcn_mfma_f32_16x16x32_bf16(
                        aF[m], bF[n], acc[m][n], 0, 0, 0);
        }
        __syncthreads();
    }

    // C/D layout: col = lane&15, row = (lane>>4)*4 + reg  [HW-verified m89]
    // Count only strict-upper pairs (srow < tcol); doubling handled in finalize.
    float num_l = 0.0f, den_l = 0.0f;
    const float* mSb = mS + (size_t)b * Sn * Kn;
    #pragma unroll
    for (int m = 0; m < 4; ++m) {
        #pragma unroll
        for (int n = 0; n < 2; ++n) {
            #pragma unroll
            for (int r = 0; r < 4; ++r) {
                const int srow = s0 + wm * 64 + m * 16 + l4 * 4 + r;
                const int tcol = t0 + wn * 32 + n * 16 + l15;
                if (acc[m][n][r] > 0.95f && srow < tcol) {
                    den_l += 1.0f;
                    const float* ma = mSb + (size_t)srow * Kn;
                    const float* mb = mSb + (size_t)tcol * Kn;
                    #pragma unroll
                    for (int k = 0; k < Kn; ++k) num_l += fabsf(ma[k] - mb[k]);
                }
            }
        }
    }

    #pragma unroll
    for (int o = 32; o > 0; o >>= 1) {
        num_l += __shfl_down(num_l, o);
        den_l += __shfl_down(den_l, o);
    }
    __shared__ float rn[8], rd[8];
    if (lane == 0) { rn[wave] = num_l; rd[wave] = den_l; }
    __syncthreads();
    if (tid == 0) {
        float nn = 0.f, dd = 0.f;
        #pragma unroll
        for (int w = 0; w < 8; ++w) { nn += rn[w]; dd += rd[w]; }
        const int bid = blockIdx.y * NTRI + blockIdx.x;
        part[2 * bid]     = nn;
        part[2 * bid + 1] = dd;
    }
}

// Reduce NPART {num,den} pairs; out = 2n / (2d + B*S + eps).
__global__ __launch_bounds__(256) void finalize_kernel(
    const float* __restrict__ part, float* __restrict__ out)
{
    const int tid = threadIdx.x;
    float n = 0.f, d = 0.f;
    #pragma unroll
    for (int i = 0; i < 2; ++i) {
        const int idx = tid + 256 * i;
        if (idx < NPART) {
            const float2 p = reinterpret_cast<const float2*>(part)[idx];
            n += p.x; d += p.y;
        }
    }
    #pragma unroll
    for (int o = 32; o > 0; o >>= 1) {
        n += __shfl_down(n, o);
        d += __shfl_down(d, o);
    }
    __shared__ float sn[4], sd[4];
    if ((tid & 63) == 0) { sn[tid >> 6] = n; sd[tid >> 6] = d; }
    __syncthreads();
    if (tid == 0) {
        const float fn = 2.0f * (sn[0] + sn[1] + sn[2] + sn[3]);
        const float fd = 2.0f * (sd[0] + sd[1] + sd[2] + sd[3])
                       + (float)(Bn * Sn);
        out[0] = fn / (fd + 1e-6f);
    }
}

extern "C" void kernel_launch(void* const* d_in, const int* in_sizes, int n_in,
                              void* d_out, int out_size, void* d_ws, size_t ws_size,
                              hipStream_t stream) {
    const float* masks   = (const float*)d_in[0];   // (B,K,H,W) fp32
    const float* feats   = (const float*)d_in[1];   // (B,C,H,W) fp32
    const int*   indices = (const int*)d_in[2];     // (B,S) int32
    float* out = (float*)d_out;

    // ws: fTb (2MB) | mS (128KB) | part (NPART*2 f32)
    const size_t fTb_b = (size_t)Bn * Sn * Cn * sizeof(ushort);
    const size_t mS_b  = (size_t)Bn * Sn * Kn * sizeof(float);

    ushort* fTb  = (ushort*)d_ws;
    float*  mSm  = (float*)((char*)d_ws + fTb_b);
    float*  part = (float*)((char*)d_ws + fTb_b + mS_b);

    dim3 gg(HWn / TLH, Bn);     // (256, 2)
    gatherT_kernel<<<gg, 256, 0, stream>>>(masks, feats, indices, fTb, mSm);
    dim3 grid(NTRI, Bn);        // (136, 2)
    sim_kernel<<<grid, 512, 0, stream>>>(fTb, mSm, part);
    finalize_kernel<<<1, 256, 0, stream>>>(part, out);
}

// Round 11
// 26.395 us; speedup vs baseline: 2.4750x; 1.0541x over previous
//
#include <hip/hip_runtime.h>
#include <hip/hip_bf16.h>
#include <math.h>

#define Bn 2
#define Kn 8
#define Cn 256
#define HWn (128*128)
#define Sn 2048
#define BT 64             // sim block output tile (4 waves, 2x2 of 32x32)
#define BKc 128           // k-slice width (ushorts) staged per LDS fill
#define NSTAGE (Cn / BKc) // 2
#define NT (Sn / BT)      // 32 tile-rows
#define NTRI (NT*(NT+1)/2)   // 528 upper-triangle blocks per batch
#define NPART (NTRI * Bn)    // 1056
#define TLH 128           // gatherT h-tile width

typedef __bf16 bf16x8 __attribute__((ext_vector_type(8)));
typedef float  f32x4  __attribute__((ext_vector_type(4)));

__device__ __forceinline__ void gload_lds16(const ushort* g, ushort* l) {
    __builtin_amdgcn_global_load_lds(
        (const __attribute__((address_space(1))) void*)g,
        (__attribute__((address_space(3))) void*)l,
        16, 0, 0);
}

__device__ __forceinline__ float bf16_to_f32(ushort u) {
    union { unsigned int i; float f; } cv;
    cv.i = ((unsigned int)u) << 16;
    return cv.f;
}
__device__ __forceinline__ ushort f32_to_bf16u(float f) {
    __hip_bfloat16 hv = __float2bfloat16(f);
    return *reinterpret_cast<const ushort*>(&hv);
}

// ---- fused gather: stream feats coalesced, keep only sampled columns ----
// One block per (b, 128-wide h-tile): 512 thr, LDS [256 c][128 h] bf16,
// membership scan, wave-per-sampled-column normalize + write + sigmoid.
__global__ __launch_bounds__(512) void gatherT_kernel(
    const float* __restrict__ masks, const float* __restrict__ feats,
    const int* __restrict__ indices, ushort* __restrict__ fTb,
    float* __restrict__ mS)
{
    __shared__ ushort tile[Cn][TLH + 4];   // stride 132 ushorts (264 B)
    __shared__ int smap[TLH];

    const int b  = blockIdx.y;
    const int h0 = blockIdx.x * TLH;
    const int t  = threadIdx.x;
    const int lane = t & 63;
    const int wave = t >> 6;

    if (t < TLH) smap[t] = -1;
    __syncthreads();

    // membership scan: 2048 indices, 4 per thread (permutation -> no races)
    #pragma unroll
    for (int i = 0; i < 4; ++i) {
        const int s  = t * 4 + i;
        const int d  = indices[b * Sn + s] - h0;
        if ((unsigned)d < TLH) smap[d] = s;
    }

    // coalesced tile load: c = (t>>5)+16*it, h4 = (t&31)*4
    const float* fb = feats + ((size_t)b * Cn) * HWn + h0;
    const int c_l = t >> 5;        // 0..15
    const int h4  = (t & 31) * 4;  // 0..124
    #pragma unroll
    for (int it = 0; it < 16; ++it) {
        const int c = c_l + 16 * it;
        const float4 v = *reinterpret_cast<const float4*>(fb + (size_t)c * HWn + h4);
        ushort4 u;
        u.x = f32_to_bf16u(v.x); u.y = f32_to_bf16u(v.y);
        u.z = f32_to_bf16u(v.z); u.w = f32_to_bf16u(v.w);
        *reinterpret_cast<ushort4*>(&tile[c][h4]) = u;
    }
    __syncthreads();

    // wave per sampled column (8 waves stride the 128 slots)
    for (int hs = wave; hs < TLH; hs += 8) {
        const int p = smap[hs];
        if (p < 0) continue;
        float v[4];
        #pragma unroll
        for (int q = 0; q < 4; ++q)
            v[q] = bf16_to_f32(tile[lane + 64 * q][hs]);
        float x = v[0]*v[0] + v[1]*v[1] + v[2]*v[2] + v[3]*v[3];
        #pragma unroll
        for (int o = 32; o > 0; o >>= 1) x += __shfl_xor(x, o);
        const float scale = 1.0f / fmaxf(sqrtf(x), 1e-12f);
        #pragma unroll
        for (int q = 0; q < 4; ++q)
            fTb[(size_t)(b * Sn + p) * Cn + lane + 64 * q] =
                f32_to_bf16u(v[q] * scale);
        if (lane < Kn) {
            const float lg = masks[((size_t)(b * Kn + lane)) * HWn + h0 + hs];
            mS[(size_t)(b * Sn + p) * Kn + lane] = 1.0f / (1.0f + expf(-lg));
        }
    }
}

// MFMA Gram matrix over upper-triangle 64x64 tile pairs (1056 blocks =
// 4.1 rounds of 256 CUs -> balanced). 4 waves (2x2) of 32x32; BK=128
// single-buffered staging, involution swizzle. Plain-store partials.
__global__ __launch_bounds__(256, 4) void sim_kernel(
    const ushort* __restrict__ fTb, const float* __restrict__ mS,
    float* __restrict__ part)
{
    __shared__ ushort ldsA[BT * BKc];   // 16 KB
    __shared__ ushort ldsB[BT * BKc];   // 16 KB

    const int b = blockIdx.y;
    // decode upper-triangle pair (i <= j) from blockIdx.x
    int i = 0, rem = blockIdx.x;
    while (rem >= NT - i) { rem -= NT - i; ++i; }
    const int j  = i + rem;
    const int s0 = i * BT;
    const int t0 = j * BT;

    const int tid = threadIdx.x;
    const int lane = tid & 63;
    const int wave = tid >> 6;          // 0..3
    const int wm = wave >> 1;           // 0..1 : 32-row slab
    const int wn = wave & 1;            // 0..1 : 32-col slab
    const int l15 = lane & 15, l4 = lane >> 4;

    const ushort* FA = fTb + ((size_t)(b * Sn + s0)) * Cn;
    const ushort* FB = fTb + ((size_t)(b * Sn + t0)) * Cn;

    f32x4 acc[2][2];
    #pragma unroll
    for (int m = 0; m < 2; ++m)
        #pragma unroll
        for (int n = 0; n < 2; ++n) acc[m][n] = (f32x4){0.f, 0.f, 0.f, 0.f};

    #pragma unroll
    for (int st = 0; st < NSTAGE; ++st) {
        const int k0 = st * BKc;
        // stage: 1024 16B-chunks/matrix; 256 thr x 4; involution swizzle
        #pragma unroll
        for (int i2 = 0; i2 < 4; ++i2) {
            const int q   = tid + i2 * 256;         // 0..1023
            const int row = q >> 4;                 // 0..63
            const int csw = (q & 15) ^ (row & 15);
            const size_t goff = (size_t)row * Cn + k0 + csw * 8;
            gload_lds16(FA + goff, &ldsA[q * 8]);
            gload_lds16(FB + goff, &ldsB[q * 8]);
        }
        __syncthreads();

        #pragma unroll
        for (int kk = 0; kk < BKc; kk += 32) {
            const int g = (kk >> 3) + l4;           // chunk 0..15
            bf16x8 aF[2], bF[2];
            #pragma unroll
            for (int m = 0; m < 2; ++m) {
                const int row = wm * 32 + m * 16 + l15;
                aF[m] = *reinterpret_cast<const bf16x8*>(
                    &ldsA[row * BKc + ((g ^ (row & 15)) << 3)]);
            }
            #pragma unroll
            for (int n = 0; n < 2; ++n) {
                const int row = wn * 32 + n * 16 + l15;
                bF[n] = *reinterpret_cast<const bf16x8*>(
                    &ldsB[row * BKc + ((g ^ (row & 15)) << 3)]);
            }
            #pragma unroll
            for (int m = 0; m < 2; ++m)
                #pragma unroll
                for (int n = 0; n < 2; ++n)
                    acc[m][n] = __builtin_amdgcn_mfma_f32_16x16x32_bf16(
                        aF[m], bF[n], acc[m][n], 0, 0, 0);
        }
        __syncthreads();
    }

    // C/D layout: col = lane&15, row = (lane>>4)*4 + reg  [HW-verified m89]
    // Count only strict-upper pairs (srow < tcol); doubled in finalize.
    float num_l = 0.0f, den_l = 0.0f;
    const float* mSb = mS + (size_t)b * Sn * Kn;
    #pragma unroll
    for (int m = 0; m < 2; ++m) {
        #pragma unroll
        for (int n = 0; n < 2; ++n) {
            #pragma unroll
            for (int r = 0; r < 4; ++r) {
                const int srow = s0 + wm * 32 + m * 16 + l4 * 4 + r;
                const int tcol = t0 + wn * 32 + n * 16 + l15;
                if (acc[m][n][r] > 0.95f && srow < tcol) {
                    den_l += 1.0f;
                    const float* ma = mSb + (size_t)srow * Kn;
                    const float* mb = mSb + (size_t)tcol * Kn;
                    #pragma unroll
                    for (int k = 0; k < Kn; ++k) num_l += fabsf(ma[k] - mb[k]);
                }
            }
        }
    }

    #pragma unroll
    for (int o = 32; o > 0; o >>= 1) {
        num_l += __shfl_down(num_l, o);
        den_l += __shfl_down(den_l, o);
    }
    __shared__ float rn[4], rd[4];
    if (lane == 0) { rn[wave] = num_l; rd[wave] = den_l; }
    __syncthreads();
    if (tid == 0) {
        const int bid = blockIdx.y * NTRI + blockIdx.x;
        part[2 * bid]     = rn[0] + rn[1] + rn[2] + rn[3];
        part[2 * bid + 1] = rd[0] + rd[1] + rd[2] + rd[3];
    }
}

// Reduce NPART {num,den} pairs; out = 2n / (2d + B*S + eps).
__global__ __launch_bounds__(256) void finalize_kernel(
    const float* __restrict__ part, float* __restrict__ out)
{
    const int tid = threadIdx.x;
    float n = 0.f, d = 0.f;
    #pragma unroll
    for (int i = 0; i < 5; ++i) {
        const int idx = tid + 256 * i;
        if (idx < NPART) {
            const float2 p = reinterpret_cast<const float2*>(part)[idx];
            n += p.x; d += p.y;
        }
    }
    #pragma unroll
    for (int o = 32; o > 0; o >>= 1) {
        n += __shfl_down(n, o);
        d += __shfl_down(d, o);
    }
    __shared__ float sn[4], sd[4];
    if ((tid & 63) == 0) { sn[tid >> 6] = n; sd[tid >> 6] = d; }
    __syncthreads();
    if (tid == 0) {
        const float fn = 2.0f * (sn[0] + sn[1] + sn[2] + sn[3]);
        const float fd = 2.0f * (sd[0] + sd[1] + sd[2] + sd[3])
                       + (float)(Bn * Sn);
        out[0] = fn / (fd + 1e-6f);
    }
}

extern "C" void kernel_launch(void* const* d_in, const int* in_sizes, int n_in,
                              void* d_out, int out_size, void* d_ws, size_t ws_size,
                              hipStream_t stream) {
    const float* masks   = (const float*)d_in[0];   // (B,K,H,W) fp32
    const float* feats   = (const float*)d_in[1];   // (B,C,H,W) fp32
    const int*   indices = (const int*)d_in[2];     // (B,S) int32
    float* out = (float*)d_out;

    // ws: fTb (2MB) | mS (128KB) | part (NPART*2 f32)
    const size_t fTb_b = (size_t)Bn * Sn * Cn * sizeof(ushort);
    const size_t mS_b  = (size_t)Bn * Sn * Kn * sizeof(float);

    ushort* fTb  = (ushort*)d_ws;
    float*  mSm  = (float*)((char*)d_ws + fTb_b);
    float*  part = (float*)((char*)d_ws + fTb_b + mS_b);

    dim3 gg(HWn / TLH, Bn);     // (128, 2)
    gatherT_kernel<<<gg, 512, 0, stream>>>(masks, feats, indices, fTb, mSm);
    dim3 grid(NTRI, Bn);        // (528, 2)
    sim_kernel<<<grid, 256, 0, stream>>>(fTb, mSm, part);
    finalize_kernel<<<1, 256, 0, stream>>>(part, out);
}